// Round 12
// baseline (495.351 us; speedup 1.0000x reference)
//
#include <hip/hip_runtime.h>

#define D 256

typedef float f32x4 __attribute__((ext_vector_type(4)));
typedef _Float16 f16x8 __attribute__((ext_vector_type(8)));

// ---------------------------------------------------------------- k_edges
__global__ void k_edges(const int* __restrict__ ei, const int* __restrict__ cl,
                        float* __restrict__ degx, int E) {
    int e = blockIdx.x * blockDim.x + threadIdx.x;
    if (e >= E) return;
    int s = ei[e];
    int d = ei[E + e];
    if (cl[s] == cl[d])
        unsafeAtomicAdd(&degx[d], 1.0f);   // HW global_atomic_add_f32, exact ints
}

// ---------------------------------------------------------------- k_init
// rows with degx>0: out_row = X_row / (degx+1), and mark cluster active
// (degx[n]>0 implies cluster cl[n] has an intra edge; idempotent store).
__global__ void k_init(const float* __restrict__ X, const float* __restrict__ degx,
                       const int* __restrict__ cl, int* __restrict__ activeC,
                       float* __restrict__ out, int N) {
    int i = blockIdx.x * blockDim.x + threadIdx.x;
    int lane = threadIdx.x & 63;
    float dx = 0.0f;
    bool hit = false;
    if (i < N) {
        dx = degx[i];
        hit = dx > 0.0f;
        if (hit) activeC[cl[i]] = 1;
    }
    unsigned long long m = __ballot(hit);
    int base = i - lane;
    while (m) {
        int b = __ffsll((long long)m) - 1;
        m &= m - 1;
        int r = base + b;
        float inv = 1.0f / (__shfl(dx, b) + 1.0f);
        float4 x = *(const float4*)(X + (size_t)r * D + lane * 4);
        x.x *= inv; x.y *= inv; x.z *= inv; x.w *= inv;
        *(float4*)(out + (size_t)r * D + lane * 4) = x;
    }
}

// ---------------------------------------------------------------- k_scatter
__global__ void k_scatter(const int* __restrict__ ei, const int* __restrict__ cl,
                          const float* __restrict__ degx, const float* __restrict__ X,
                          float* __restrict__ out, int E) {
    int e = blockIdx.x * blockDim.x + threadIdx.x;
    int lane = threadIdx.x & 63;
    int s = 0, d = 0;
    bool intra = false;
    if (e < E) {
        s = ei[e];
        d = ei[E + e];
        intra = (cl[s] == cl[d]);
    }
    unsigned long long mask = __ballot(intra);
    while (mask) {
        int b = __ffsll((long long)mask) - 1;
        mask &= mask - 1;
        int ss = __shfl(s, b);
        int dd = __shfl(d, b);
        float norm = rsqrtf((degx[ss] + 1.0f) * (degx[dd] + 1.0f));
        float4 xv = *(const float4*)(X + (size_t)ss * D + lane * 4);
        float* op = out + (size_t)dd * D + lane * 4;
        unsafeAtomicAdd(op + 0, norm * xv.x);
        unsafeAtomicAdd(op + 1, norm * xv.y);
        unsafeAtomicAdd(op + 2, norm * xv.z);
        unsafeAtomicAdd(op + 3, norm * xv.w);
    }
}

// ---------------------------------------------------------------- k_prepw
// Pack W (f32 [k][n]) into f16 fragment layout (operand-role symmetric):
//   Wp[((ks*16+ct)*64 + lane)*8 + i] = W[ks*32 + h*8 + i][ct*16 + cn],
// lane = h*16 + cn.
__global__ void k_prepw(const float* __restrict__ W, _Float16* __restrict__ Wp) {
    int idx = blockIdx.x * blockDim.x + threadIdx.x;
    if (idx >= D * D) return;
    int k = idx >> 8, n = idx & 255;
    int ks = k >> 5, kk = k & 31;
    int h = kk >> 3, i = kk & 7;
    int ct = n >> 4, cn = n & 15;
    int lane = h * 16 + cn;
    Wp[(((ks * 16 + ct) * 64 + lane) << 3) + i] = (_Float16)W[idx];
}

// ---------------------------------------------------------------- k_gemm
// Round-9 structure: 256 blocks x 1024 thr, full W (128 KB) + bias (1 KB) in
// LDS staged once, one wave = one full 16x256 tile, global sweep order
// t = blk*16 + wid + r*4096 (dense band, L2-friendly; round-7/10 showed
// chunking or extra streams thrash L2).
// New vs round 9: SWAPPED mfma(wf, af) -> lane holds C[row=rA][ct*16+h*4+..]
// => 16 float4 stores/tile-wave (was 64 scalar); acc init from LDS bias;
// 1-ahead in-tile A double-buffer (loads overlap the 16-MFMA block).
__global__ __launch_bounds__(1024, 4) void k_gemm(
        const _Float16* __restrict__ Wp, const float* __restrict__ bias,
        const float* __restrict__ X, const float* __restrict__ degx,
        const int* __restrict__ cl, const int* __restrict__ activeC,
        float* __restrict__ out, int N) {
    extern __shared__ char smem[];
    _Float16* Wl = (_Float16*)smem;          // 128 KB packed W
    float* Bl = (float*)(smem + 131072);     // 1 KB bias

    int tid = threadIdx.x;
    int lane = tid & 63;
    int wid  = tid >> 6;
    int rA = lane & 15;   // node row within tile
    int h  = lane >> 4;   // k-subgroup / output col subgroup

    if (tid < 256) Bl[tid] = bias[tid];
    {
        const char* src = (const char*)Wp + tid * 16;
        #pragma unroll
        for (int it = 0; it < 8; ++it) {
            __builtin_amdgcn_global_load_lds(
                (const __attribute__((address_space(1))) void*)(src + it * 16384),
                (__attribute__((address_space(3))) void*)(smem + tid * 16 + it * 16384),
                16, 0, 0);
        }
    }
    __syncthreads();                          // drains stage (vmcnt(0))

    int T = (N + 15) >> 4;                    // 16-row tiles
    for (int t = (int)blockIdx.x * 16 + wid; t < T; t += 4096) {
        long rr = (long)t * 16 + rA;
        long rc = (rr < (long)N) ? rr : (long)N - 1;
        const float* arow = ((degx[rc] > 0.0f) ? out : X) + rc * D;
        int act = activeC[cl[rc]];
        unsigned long long bad = __ballot(act == 0 || rr >= (long)N);

        // acc = bias (C col = ct*16 + h*4 + jj)
        f32x4 acc[16];
        #pragma unroll
        for (int ct = 0; ct < 16; ++ct)
            acc[ct] = *(const f32x4*)(Bl + ct * 16 + h * 4);

        // 1-ahead double-buffered A fragments
        float4 Pa = *(const float4*)(arow + h * 8);
        float4 Pb = *(const float4*)(arow + h * 8 + 4);
        #pragma unroll
        for (int ks = 0; ks < 8; ++ks) {
            float4 a0 = Pa, a1 = Pb;
            if (ks < 7) {
                Pa = *(const float4*)(arow + (ks + 1) * 32 + h * 8);
                Pb = *(const float4*)(arow + (ks + 1) * 32 + h * 8 + 4);
            }
            f16x8 af;
            af[0]=(_Float16)a0.x; af[1]=(_Float16)a0.y; af[2]=(_Float16)a0.z; af[3]=(_Float16)a0.w;
            af[4]=(_Float16)a1.x; af[5]=(_Float16)a1.y; af[6]=(_Float16)a1.z; af[7]=(_Float16)a1.w;
            #pragma unroll
            for (int ct = 0; ct < 16; ++ct) {
                f16x8 wf = *(const f16x8*)&Wl[(((ks * 16 + ct) * 64) + lane) << 3];
                acc[ct] = __builtin_amdgcn_mfma_f32_16x16x32_f16(wf, af, acc[ct], 0, 0, 0);
            }
        }

        // epilogue: lane's row = rc, cols ct*16 + h*4 .. +3  -> float4 stores
        float* orow = out + rc * D + h * 4;
        if (bad == 0ULL) {
            #pragma unroll
            for (int ct = 0; ct < 16; ++ct)
                *(float4*)(orow + ct * 16) =
                    (float4){acc[ct][0], acc[ct][1], acc[ct][2], acc[ct][3]};
        } else if (rr < (long)N) {
            const float* xrow = X + rc * D + h * 4;
            #pragma unroll
            for (int ct = 0; ct < 16; ++ct) {
                float4 v;
                if (act) v = (float4){acc[ct][0], acc[ct][1], acc[ct][2], acc[ct][3]};
                else     v = *(const float4*)(xrow + ct * 16);
                *(float4*)(orow + ct * 16) = v;
            }
        }
    }
}

// ---------------------------------------------------------------- launch
extern "C" void kernel_launch(void* const* d_in, const int* in_sizes, int n_in,
                              void* d_out, int out_size, void* d_ws, size_t ws_size,
                              hipStream_t stream) {
    const float* X    = (const float*)d_in[0];
    const float* W    = (const float*)d_in[1];
    const float* bias = (const float*)d_in[2];
    const int*   cl   = (const int*)d_in[3];
    const int*   ei   = (const int*)d_in[4];
    int N = in_sizes[3];
    int E = in_sizes[4] / 2;
    float* out = (float*)d_out;

    char* ws = (char*)d_ws;
    float* degx = (float*)ws;                                  // N floats, zeroed
    size_t off = ((size_t)N * sizeof(float) + 255) & ~(size_t)255;
    int* activeC = (int*)(ws + off);                           // 64 ints, zeroed
    size_t zbytes = off + 256;
    _Float16* Wp = (_Float16*)(ws + ((zbytes + 255) & ~(size_t)255));  // 128 KB

    hipFuncSetAttribute((const void*)k_gemm,
                        hipFuncAttributeMaxDynamicSharedMemorySize, 135168);

    hipMemsetAsync(ws, 0, zbytes, stream);
    k_prepw<<<(D * D + 255) / 256, 256, 0, stream>>>(W, Wp);
    k_edges<<<(E + 255) / 256, 256, 0, stream>>>(ei, cl, degx, E);
    k_init<<<(N + 255) / 256, 256, 0, stream>>>(X, degx, cl, activeC, out, N);
    k_scatter<<<(E + 255) / 256, 256, 0, stream>>>(ei, cl, degx, X, out, E);
    k_gemm<<<256, 1024, 132096, stream>>>(Wp, bias, X, degx, cl, activeC, out, N);
}

// Round 13
// 132.376 us; speedup vs baseline: 3.7420x; 3.7420x over previous
//
#include <hip/hip_runtime.h>

#define D 256

typedef float f32x4 __attribute__((ext_vector_type(4)));
typedef _Float16 f16x8 __attribute__((ext_vector_type(8)));

// ---------------------------------------------------------------- k_edges
__global__ void k_edges(const int* __restrict__ ei, const int* __restrict__ cl,
                        float* __restrict__ degx, int E) {
    int e = blockIdx.x * blockDim.x + threadIdx.x;
    if (e >= E) return;
    int s = ei[e];
    int d = ei[E + e];
    if (cl[s] == cl[d])
        unsafeAtomicAdd(&degx[d], 1.0f);   // HW global_atomic_add_f32, exact ints
}

// ---------------------------------------------------------------- k_init
// rows with degx>0: out_row = X_row / (degx+1), and mark cluster active
// (degx[n]>0 implies cluster cl[n] has an intra edge; idempotent store).
__global__ void k_init(const float* __restrict__ X, const float* __restrict__ degx,
                       const int* __restrict__ cl, int* __restrict__ activeC,
                       float* __restrict__ out, int N) {
    int i = blockIdx.x * blockDim.x + threadIdx.x;
    int lane = threadIdx.x & 63;
    float dx = 0.0f;
    bool hit = false;
    if (i < N) {
        dx = degx[i];
        hit = dx > 0.0f;
        if (hit) activeC[cl[i]] = 1;
    }
    unsigned long long m = __ballot(hit);
    int base = i - lane;
    while (m) {
        int b = __ffsll((long long)m) - 1;
        m &= m - 1;
        int r = base + b;
        float inv = 1.0f / (__shfl(dx, b) + 1.0f);
        float4 x = *(const float4*)(X + (size_t)r * D + lane * 4);
        x.x *= inv; x.y *= inv; x.z *= inv; x.w *= inv;
        *(float4*)(out + (size_t)r * D + lane * 4) = x;
    }
}

// ---------------------------------------------------------------- k_scatter
__global__ void k_scatter(const int* __restrict__ ei, const int* __restrict__ cl,
                          const float* __restrict__ degx, const float* __restrict__ X,
                          float* __restrict__ out, int E) {
    int e = blockIdx.x * blockDim.x + threadIdx.x;
    int lane = threadIdx.x & 63;
    int s = 0, d = 0;
    bool intra = false;
    if (e < E) {
        s = ei[e];
        d = ei[E + e];
        intra = (cl[s] == cl[d]);
    }
    unsigned long long mask = __ballot(intra);
    while (mask) {
        int b = __ffsll((long long)mask) - 1;
        mask &= mask - 1;
        int ss = __shfl(s, b);
        int dd = __shfl(d, b);
        float norm = rsqrtf((degx[ss] + 1.0f) * (degx[dd] + 1.0f));
        float4 xv = *(const float4*)(X + (size_t)ss * D + lane * 4);
        float* op = out + (size_t)dd * D + lane * 4;
        unsafeAtomicAdd(op + 0, norm * xv.x);
        unsafeAtomicAdd(op + 1, norm * xv.y);
        unsafeAtomicAdd(op + 2, norm * xv.z);
        unsafeAtomicAdd(op + 3, norm * xv.w);
    }
}

// ---------------------------------------------------------------- k_prepw
// Pack W (f32 [k][n]) into f16 fragment layout:
//   Wp[((ks*16+ct)*64 + lane)*8 + i] = W[ks*32 + h*8 + i][ct*16 + cn],
// lane = h*16 + cn.
__global__ void k_prepw(const float* __restrict__ W, _Float16* __restrict__ Wp) {
    int idx = blockIdx.x * blockDim.x + threadIdx.x;
    if (idx >= D * D) return;
    int k = idx >> 8, n = idx & 255;
    int ks = k >> 5, kk = k & 31;
    int h = kk >> 3, i = kk & 7;
    int ct = n >> 4, cn = n & 15;
    int lane = h * 16 + cn;
    Wp[(((ks * 16 + ct) * 64 + lane) << 3) + i] = (_Float16)W[idx];
}

// ---------------------------------------------------------------- k_gemm
// ROUND-9 STRUCTURE VERBATIM (67us, FETCH 67MB / WRITE 121MB proven):
// 256 blocks x 1024 thr, full W (128 KB) in LDS staged once, one wave = one
// 16x256 tile, UNSWAPPED mfma(af, wf) -> lane-row-contiguous stores (16
// consecutive lanes write 64 contiguous bytes of ONE row; the swapped variant's
// 16-row scatter amplified DRAM traffic 5-6x in rounds 11/12). Global sweep
// order t = blk*16 + wid + r*4096 (dense band, L2-friendly).
// Single change vs round 9: 1-ahead in-tile A double-buffer (same addresses,
// earlier issue -> higher memory duty cycle).
__global__ __launch_bounds__(1024, 4) void k_gemm(
        const _Float16* __restrict__ Wp, const float* __restrict__ bias,
        const float* __restrict__ X, const float* __restrict__ degx,
        const int* __restrict__ cl, const int* __restrict__ activeC,
        float* __restrict__ out, int N) {
    extern __shared__ _Float16 Wl[];           // 128 KB: all of Wp
    int tid  = threadIdx.x;
    int lane = tid & 63;
    int wid  = tid >> 6;
    int rA = lane & 15;   // A row within 16-row tile
    int h  = lane >> 4;   // k-subgroup
    int cn = lane & 15;   // output col within ct tile

    // one-time stage: 128 KB = 8 iters x (1024 threads x 16 B)
    {
        const char* src = (const char*)Wp + tid * 16;
        #pragma unroll
        for (int it = 0; it < 8; ++it) {
            __builtin_amdgcn_global_load_lds(
                (const __attribute__((address_space(1))) void*)(src + it * 16384),
                (__attribute__((address_space(3))) void*)((char*)Wl + tid * 16 + it * 16384),
                16, 0, 0);
        }
    }
    float bv[16];
    #pragma unroll
    for (int ct = 0; ct < 16; ++ct) bv[ct] = bias[ct * 16 + cn];
    __syncthreads();                            // drains stage (vmcnt(0))

    int T = (N + 15) >> 4;                      // 16-row tiles
    for (int t = (int)blockIdx.x * 16 + wid; t < T; t += 4096) {
        long r = (long)t * 16 + rA;
        if (r > (long)N - 1) r = (long)N - 1;
        const float* arow = ((degx[r] > 0.0f) ? out : X) + r * D;

        f32x4 acc[16];
        #pragma unroll
        for (int ct = 0; ct < 16; ++ct) acc[ct] = (f32x4){0.f, 0.f, 0.f, 0.f};

        // 1-ahead double-buffered A fragments (same addresses as round 9)
        float4 Pa = *(const float4*)(arow + h * 8);
        float4 Pb = *(const float4*)(arow + h * 8 + 4);
        #pragma unroll
        for (int ks = 0; ks < 8; ++ks) {
            float4 a0 = Pa, a1 = Pb;
            if (ks < 7) {
                Pa = *(const float4*)(arow + (ks + 1) * 32 + h * 8);
                Pb = *(const float4*)(arow + (ks + 1) * 32 + h * 8 + 4);
            }
            f16x8 af;
            af[0]=(_Float16)a0.x; af[1]=(_Float16)a0.y; af[2]=(_Float16)a0.z; af[3]=(_Float16)a0.w;
            af[4]=(_Float16)a1.x; af[5]=(_Float16)a1.y; af[6]=(_Float16)a1.z; af[7]=(_Float16)a1.w;
            #pragma unroll
            for (int ct = 0; ct < 16; ++ct) {
                f16x8 wf = *(const f16x8*)&Wl[(((ks * 16 + ct) * 64) + lane) << 3];
                acc[ct] = __builtin_amdgcn_mfma_f32_16x16x32_f16(af, wf, acc[ct], 0, 0, 0);
            }
        }

        // epilogue: D layout col = ct*16 + cn, row = h*4 + j.
        // Fast path (all rows active, no tail): pure acc+bias stores, no X read.
        #pragma unroll
        for (int j = 0; j < 4; ++j) {
            long rr = (long)t * 16 + h * 4 + j;
            bool ok = rr < (long)N;
            long rc = ok ? rr : (long)N - 1;
            bool act = activeC[cl[rc]] != 0;
            unsigned long long bad = __ballot(!act || !ok);
            float* orow = out + rc * D;
            if (bad == 0ULL) {
                #pragma unroll
                for (int ct = 0; ct < 16; ++ct)
                    orow[ct * 16 + cn] = acc[ct][j] + bv[ct];
            } else if (ok) {
                const float* xrow = X + rc * D;
                #pragma unroll
                for (int ct = 0; ct < 16; ++ct) {
                    float v = acc[ct][j] + bv[ct];
                    if (!act) v = xrow[ct * 16 + cn];
                    orow[ct * 16 + cn] = v;
                }
            }
        }
    }
}

// ---------------------------------------------------------------- launch
extern "C" void kernel_launch(void* const* d_in, const int* in_sizes, int n_in,
                              void* d_out, int out_size, void* d_ws, size_t ws_size,
                              hipStream_t stream) {
    const float* X    = (const float*)d_in[0];
    const float* W    = (const float*)d_in[1];
    const float* bias = (const float*)d_in[2];
    const int*   cl   = (const int*)d_in[3];
    const int*   ei   = (const int*)d_in[4];
    int N = in_sizes[3];
    int E = in_sizes[4] / 2;
    float* out = (float*)d_out;

    char* ws = (char*)d_ws;
    float* degx = (float*)ws;                                  // N floats, zeroed
    size_t off = ((size_t)N * sizeof(float) + 255) & ~(size_t)255;
    int* activeC = (int*)(ws + off);                           // 64 ints, zeroed
    size_t zbytes = off + 256;
    _Float16* Wp = (_Float16*)(ws + ((zbytes + 255) & ~(size_t)255));  // 128 KB

    hipFuncSetAttribute((const void*)k_gemm,
                        hipFuncAttributeMaxDynamicSharedMemorySize, 131072);

    hipMemsetAsync(ws, 0, zbytes, stream);
    k_prepw<<<(D * D + 255) / 256, 256, 0, stream>>>(W, Wp);
    k_edges<<<(E + 255) / 256, 256, 0, stream>>>(ei, cl, degx, E);
    k_init<<<(N + 255) / 256, 256, 0, stream>>>(X, degx, cl, activeC, out, N);
    k_scatter<<<(E + 255) / 256, 256, 0, stream>>>(ei, cl, degx, X, out, E);
    k_gemm<<<256, 1024, 131072, stream>>>(Wp, bias, X, degx, cl, activeC, out, N);
}